// Round 5
// baseline (456.250 us; speedup 1.0000x reference)
//
#include <hip/hip_runtime.h>

// GenSP: B=4, C=64, H=W=256, st=16 -> nH=nW=16, nS=256, P=65536
// out (B,nS,P) = 256MB dense, <=9 nonzeros per pixel column.
// M_COEF=0 -> grid channels zero; f2 (pixel norm) cancels in softmax.
// ws float layout: num[65536] den[1024] cent0[65536]

#define PP 65536

// ---- init: 16x16 block means -> cent0[(b*256+s)*64+c]; zero num/den ----
__global__ __launch_bounds__(256) void k_init(const float* __restrict__ x,
                                              float* __restrict__ cent0,
                                              float4* __restrict__ zero4) {
  __shared__ float blk[64];
  int t = threadIdx.x;
  int wg = blockIdx.x;
  int cg = wg & 15, bi = (wg >> 4) & 15, b = wg >> 8;
  int tid = wg * 256 + t;
  if (tid < 16640) zero4[tid] = make_float4(0.f, 0.f, 0.f, 0.f);  // num+den
  if (t < 64) blk[t] = 0.f;
  __syncthreads();
  int sub = t >> 6, j4 = t & 63;
#pragma unroll
  for (int q = 0; q < 4; q++) {
    int c = cg * 4 + q;
    const float4* xp4 =
        (const float4*)(x + ((long)(b * 64 + c) << 16) + ((bi * 16 + sub * 4) << 8)) + j4;
    float4 a = make_float4(0.f, 0.f, 0.f, 0.f);
#pragma unroll
    for (int r = 0; r < 4; r++) {
      float4 v = xp4[r * 64];
      a.x += v.x; a.y += v.y; a.z += v.z; a.w += v.w;
    }
    float ps = a.x + a.y + a.z + a.w;
    ps += __shfl_xor(ps, 1);
    ps += __shfl_xor(ps, 2);
    if ((j4 & 3) == 0) atomicAdd(&blk[(j4 >> 2) * 4 + q], ps);
  }
  __syncthreads();
  if (t < 64) {
    int sj = t >> 2, q = t & 3;
    cent0[(((b << 8) + bi * 16 + sj) << 6) + cg * 4 + q] = blk[t] * (1.f / 256.f);
  }
}

// ---- stat: strip = 8 rows x 64 cols, 2 px/thread; num/den accumulation ----
__global__ __launch_bounds__(256) void k_stat(const float* __restrict__ x,
                                              const float* __restrict__ cent,
                                              float* __restrict__ num,
                                              float* __restrict__ den) {
  __shared__ float cent_s[18 * 68];
  __shared__ float c2p[144];
  __shared__ float c2_s[18];
  __shared__ float red_s[2340];

  int t = threadIdx.x;
  int wg = blockIdx.x;  // 512 = b(4) x bi(16) x sx(4) x half(2)
  int half = wg & 1, sx = (wg >> 1) & 3, bi = (wg >> 3) & 15, b = wg >> 7;

  for (int o = t; o < 2340; o += 256) red_s[o] = 0.f;

  for (int o = t; o < 288; o += 256) {
    int lc = o >> 4, f4i = o & 15;
    int ci = min(max(bi - 1 + lc / 6, 0), 15);
    int cj = min(max(sx * 4 - 1 + lc % 6, 0), 15);
    float4 v = *(const float4*)(cent + (((b << 8) + ci * 16 + cj) << 6) + f4i * 4);
    *(float4*)&cent_s[lc * 68 + f4i * 4] = v;
  }
  __syncthreads();
  if (t < 144) {
    int lc = t >> 3, pt = t & 7;
    float s = 0.f;
#pragma unroll
    for (int m = 0; m < 8; m++) { float v = cent_s[lc * 68 + pt * 8 + m]; s += v * v; }
    c2p[t] = s;
  }
  __syncthreads();
  if (t < 18) {
    float s = 0.f;
#pragma unroll
    for (int m = 0; m < 8; m++) s += c2p[t * 8 + m];
    c2_s[t] = s;
  }
  __syncthreads();

  int r = t >> 5, g = t & 31;
  int row = bi * 16 + half * 8 + r;
  int col = sx * 64 + g * 2;
  int lb = g >> 3;
  int bjb = sx * 4 + lb;

  int cidx[9];
  float c2k[9];
  int vbits = 0;
#pragma unroll
  for (int k = 0; k < 9; k++) {
    int di = k / 3 - 1, dj = k % 3 - 1;
    int ciu = bi + di, cju = bjb + dj;
    if ((unsigned)ciu < 16u && (unsigned)cju < 16u) vbits |= 1 << k;
    int lidx = (di + 1) * 6 + (lb + 1 + dj);
    cidx[k] = lidx * 68;
    c2k[k] = c2_s[lidx];
  }

  const float* base = x + ((long)(b * 64) << 16) + row * 256 + col;

  float acc0[9], acc1[9];
#pragma unroll
  for (int k = 0; k < 9; k++) { acc0[k] = 0.f; acc1[k] = 0.f; }
#pragma unroll 4
  for (int c = 0; c < 64; c++) {
    float2 xv = *(const float2*)(base + ((long)c << 16));
#pragma unroll
    for (int k = 0; k < 9; k++) {
      float cv = cent_s[cidx[k] + c];
      acc0[k] = fmaf(xv.x, cv, acc0[k]);
      acc1[k] = fmaf(xv.y, cv, acc1[k]);
    }
  }

  float mx0 = -1e30f, mx1 = -1e30f;
#pragma unroll
  for (int k = 0; k < 9; k++) {
    float l0 = 2.f * acc0[k] - c2k[k];
    float l1 = 2.f * acc1[k] - c2k[k];
    bool v = (vbits >> k) & 1;
    acc0[k] = v ? l0 : -1e30f;
    acc1[k] = v ? l1 : -1e30f;
    mx0 = fmaxf(mx0, acc0[k]);
    mx1 = fmaxf(mx1, acc1[k]);
  }
  float s0 = 0.f, s1 = 0.f;
#pragma unroll
  for (int k = 0; k < 9; k++) {
    acc0[k] = __expf(acc0[k] - mx0);
    acc1[k] = __expf(acc1[k] - mx1);
    s0 += acc0[k];
    s1 += acc1[k];
  }
  float rs0 = 1.f / s0, rs1 = 1.f / s1;
#pragma unroll
  for (int k = 0; k < 9; k++) { acc0[k] *= rs0; acc1[k] *= rs1; }

  int lane = t & 63;
  bool desig = (lane & 39) == 0;

#pragma unroll
  for (int k = 0; k < 9; k++) {
    float w = acc0[k] + acc1[k];
    w += __shfl_xor(w, 1);
    w += __shfl_xor(w, 2);
    w += __shfl_xor(w, 4);
    w += __shfl_xor(w, 32);
    if (desig) atomicAdd(&red_s[2304 + lb * 9 + k], w);
  }
#pragma unroll 2
  for (int c = 0; c < 64; c++) {
    float2 xv = *(const float2*)(base + ((long)c << 16));
#pragma unroll
    for (int k = 0; k < 9; k++) {
      float w = xv.x * acc0[k] + xv.y * acc1[k];
      w += __shfl_xor(w, 1);
      w += __shfl_xor(w, 2);
      w += __shfl_xor(w, 4);
      w += __shfl_xor(w, 32);
      if (desig) atomicAdd(&red_s[(lb * 9 + k) * 64 + c], w);
    }
  }
  __syncthreads();
  for (int o = t; o < 2340; o += 256) {
    if (o < 2304) {
      int lb2 = o / 576, rm = o - lb2 * 576;
      int k = rm >> 6, c = rm & 63;
      int di = k / 3 - 1, dj = k % 3 - 1;
      int ciu = bi + di, cju = sx * 4 + lb2 + dj;
      if ((unsigned)ciu < 16u && (unsigned)cju < 16u)
        atomicAdd(&num[(((b << 8) + ciu * 16 + cju) << 6) + c], red_s[o]);
    } else {
      int idx = o - 2304;
      int lb2 = idx / 9, k = idx - lb2 * 9;
      int di = k / 3 - 1, dj = k % 3 - 1;
      int ciu = bi + di, cju = sx * 4 + lb2 + dj;
      if ((unsigned)ciu < 16u && (unsigned)cju < 16u)
        atomicAdd(&den[(b << 8) + ciu * 16 + cju], red_s[o]);
    }
  }
}

// ---- out: finalize cents + affinity for 4 rows + contiguous 4KB writes ----
// grid 256 = b(4) x i4(64). Each thread owns 4 adjacent pixels (same block).
__global__ __launch_bounds__(256) void k_out(const float* __restrict__ x,
                                             const float* __restrict__ num,
                                             const float* __restrict__ den,
                                             float4* __restrict__ out4) {
  __shared__ float cent_s[48 * 68];   // block rows bi-1..bi+1 x 16 cols
  __shared__ float den_s[48];
  __shared__ float c2p[384];
  __shared__ float c2_s[48];
  __shared__ float aff_t[9 * 1032];   // [k][r*256+j], padded plane

  int t = threadIdx.x;
  int wg = blockIdx.x;                // 256 = b(4) x i4(64)
  int i4 = wg & 63, b = wg >> 6;
  int i0 = i4 << 2;                   // 4 rows i0..i0+3 (same block row)
  int bi = i4 >> 2;

  if (t < 48) {
    int ci = min(max(bi - 1 + (t >> 4), 0), 15);
    int cj = t & 15;
    den_s[t] = den[(b << 8) + ci * 16 + cj] + 1e-16f;
  }
  __syncthreads();
  for (int o = t; o < 768; o += 256) {
    int lr = o >> 4, f4i = o & 15;
    int ci = min(max(bi - 1 + (lr >> 4), 0), 15);
    int cj = lr & 15;
    float4 v = *(const float4*)(num + (((b << 8) + ci * 16 + cj) << 6) + f4i * 4);
    float inv = 1.f / den_s[lr];
    v.x *= inv; v.y *= inv; v.z *= inv; v.w *= inv;
    *(float4*)&cent_s[lr * 68 + f4i * 4] = v;
  }
  __syncthreads();
  for (int o = t; o < 384; o += 256) {
    int lr = o >> 3, pt = o & 7;
    float s = 0.f;
#pragma unroll
    for (int m = 0; m < 8; m++) { float v = cent_s[lr * 68 + pt * 8 + m]; s += v * v; }
    c2p[o] = s;
  }
  __syncthreads();
  if (t < 48) {
    float s = 0.f;
#pragma unroll
    for (int m = 0; m < 8; m++) s += c2p[t * 8 + m];
    c2_s[t] = s;
  }
  __syncthreads();

  // phase 1: thread t -> row i0+(t>>6), cols 4*(t&63)..+3 (one float4)
  int r = t >> 6, j4 = t & 63;
  int row = i0 + r;
  int bj = j4 >> 2;                   // block col (uniform over the 4 px)
  int cidx[9];
  float c2k[9];
  int vbits = 0;
#pragma unroll
  for (int k = 0; k < 9; k++) {
    int di = k / 3 - 1, dj = k % 3 - 1;
    int ciu = bi + di, cju = bj + dj;
    if ((unsigned)ciu < 16u && (unsigned)cju < 16u) vbits |= 1 << k;
    int lidx = (di + 1) * 16 + min(max(cju, 0), 15);
    cidx[k] = lidx * 68;
    c2k[k] = c2_s[lidx];
  }
  const float4* base = (const float4*)(x + ((long)(b * 64) << 16) + (row << 8)) + j4;
  float a0[9], a1[9], a2[9], a3[9];
#pragma unroll
  for (int k = 0; k < 9; k++) { a0[k] = 0.f; a1[k] = 0.f; a2[k] = 0.f; a3[k] = 0.f; }
#pragma unroll 8
  for (int c = 0; c < 64; c++) {
    float4 xv = base[c << 14];
#pragma unroll
    for (int k = 0; k < 9; k++) {
      float cv = cent_s[cidx[k] + c];
      a0[k] = fmaf(xv.x, cv, a0[k]);
      a1[k] = fmaf(xv.y, cv, a1[k]);
      a2[k] = fmaf(xv.z, cv, a2[k]);
      a3[k] = fmaf(xv.w, cv, a3[k]);
    }
  }
  float m0 = -1e30f, m1 = -1e30f, m2 = -1e30f, m3 = -1e30f;
#pragma unroll
  for (int k = 0; k < 9; k++) {
    bool v = (vbits >> k) & 1;
    a0[k] = v ? (2.f * a0[k] - c2k[k]) : -1e30f;
    a1[k] = v ? (2.f * a1[k] - c2k[k]) : -1e30f;
    a2[k] = v ? (2.f * a2[k] - c2k[k]) : -1e30f;
    a3[k] = v ? (2.f * a3[k] - c2k[k]) : -1e30f;
    m0 = fmaxf(m0, a0[k]); m1 = fmaxf(m1, a1[k]);
    m2 = fmaxf(m2, a2[k]); m3 = fmaxf(m3, a3[k]);
  }
  float s0 = 0.f, s1 = 0.f, s2 = 0.f, s3 = 0.f;
#pragma unroll
  for (int k = 0; k < 9; k++) {
    a0[k] = __expf(a0[k] - m0); s0 += a0[k];
    a1[k] = __expf(a1[k] - m1); s1 += a1[k];
    a2[k] = __expf(a2[k] - m2); s2 += a2[k];
    a3[k] = __expf(a3[k] - m3); s3 += a3[k];
  }
  float r0 = 1.f / s0, r1 = 1.f / s1, r2 = 1.f / s2, r3 = 1.f / s3;
#pragma unroll
  for (int k = 0; k < 9; k++)
    *(float4*)&aff_t[k * 1032 + t * 4] =
        make_float4(a0[k] * r0, a1[k] * r1, a2[k] * r2, a3[k] * r3);
  __syncthreads();

  // phase B: for each s, wg writes one contiguous 4KB chunk out[b][s][i0..i0+3][:]
  // (b,s) plane = 16384 float4 -> stride s<<14 (NOT <<12 — round-4 bug).
  float4* obase = out4 + ((long)b << 22) + (i0 << 6) + t;
  int jb = (t & 63) >> 2;             // block col of this thread's float4
#pragma unroll 4
  for (int s = 0; s < 256; s++) {
    float4 v = make_float4(0.f, 0.f, 0.f, 0.f);
    int di = (s >> 4) - bi;
    int dj = (s & 15) - jb;
    if ((unsigned)(di + 1) <= 2u && (unsigned)(dj + 1) <= 2u) {
      int k = (di + 1) * 3 + (dj + 1);
      v = *(const float4*)&aff_t[k * 1032 + t * 4];
    }
    obase[(long)s << 14] = v;
  }
}

extern "C" void kernel_launch(void* const* d_in, const int* in_sizes, int n_in,
                              void* d_out, int out_size, void* d_ws, size_t ws_size,
                              hipStream_t stream) {
  const float* x = (const float*)d_in[0];
  float* out = (float*)d_out;
  float* ws = (float*)d_ws;

  float* num   = ws;
  float* den   = ws + 65536;
  float* cent0 = ws + 66560;

  k_init<<<1024, 256, 0, stream>>>(x, cent0, (float4*)ws);
  k_stat<<<512, 256, 0, stream>>>(x, cent0, num, den);
  k_out<<<256, 256, 0, stream>>>(x, num, den, (float4*)out);
}

// Round 6
// 358.628 us; speedup vs baseline: 1.2722x; 1.2722x over previous
//
#include <hip/hip_runtime.h>

// GenSP: B=4, C=64, H=W=256, st=16 -> nH=nW=16, nS=256, P=65536
// out (B,nS,P) = 256MB dense, <=9 nonzeros per pixel column.
// M_COEF=0 -> grid channels zero; f2 (pixel norm) cancels in softmax.
// ws float layout: num[65536] den[1024] cent0[65536]

#define PP 65536

typedef __attribute__((ext_vector_type(8))) short short8;
typedef __attribute__((ext_vector_type(4))) float f32x4;

__device__ __forceinline__ unsigned short f2bf(float f) {
  unsigned u = __float_as_uint(f);
  u += 0x7fff + ((u >> 16) & 1);   // round-nearest-even
  return (unsigned short)(u >> 16);
}

// ---- init: 16x16 block means -> cent0[(b*256+s)*64+c]; zero num/den ----
__global__ __launch_bounds__(256) void k_init(const float* __restrict__ x,
                                              float* __restrict__ cent0,
                                              float4* __restrict__ zero4) {
  __shared__ float blk[64];
  int t = threadIdx.x;
  int wg = blockIdx.x;
  int cg = wg & 15, bi = (wg >> 4) & 15, b = wg >> 8;
  int tid = wg * 256 + t;
  if (tid < 16640) zero4[tid] = make_float4(0.f, 0.f, 0.f, 0.f);  // num+den
  if (t < 64) blk[t] = 0.f;
  __syncthreads();
  int sub = t >> 6, j4 = t & 63;
#pragma unroll
  for (int q = 0; q < 4; q++) {
    int c = cg * 4 + q;
    const float4* xp4 =
        (const float4*)(x + ((long)(b * 64 + c) << 16) + ((bi * 16 + sub * 4) << 8)) + j4;
    float4 a = make_float4(0.f, 0.f, 0.f, 0.f);
#pragma unroll
    for (int r = 0; r < 4; r++) {
      float4 v = xp4[r * 64];
      a.x += v.x; a.y += v.y; a.z += v.z; a.w += v.w;
    }
    float ps = a.x + a.y + a.z + a.w;
    ps += __shfl_xor(ps, 1);
    ps += __shfl_xor(ps, 2);
    if ((j4 & 3) == 0) atomicAdd(&blk[(j4 >> 2) * 4 + q], ps);
  }
  __syncthreads();
  if (t < 64) {
    int sj = t >> 2, q = t & 3;
    cent0[(((b << 8) + bi * 16 + sj) << 6) + cg * 4 + q] = blk[t] * (1.f / 256.f);
  }
}

// ---- stat: wg = one 16x16 block; dot+softmax scalar, num via bf16 MFMA ----
// num_blk(64c x 9k) = X_blk(64x256) . aff(256x9): M=64 (4 wave-tiles), K=256, N=9.
__global__ __launch_bounds__(256) void k_stat(const float* __restrict__ x,
                                              const float* __restrict__ cent,
                                              float* __restrict__ num,
                                              float* __restrict__ den) {
  __shared__ __align__(16) unsigned short xbf[64 * 264];    // bf16 x [c][p], pad 264
  __shared__ __align__(16) unsigned short affbf[16 * 264];  // bf16 aff^T [k][p], pad 264
  __shared__ float cent_s[9 * 64];
  __shared__ float c2p[72];
  __shared__ float c2_s[9];
  __shared__ float den_s[36];
  __shared__ int scand[9];

  int t = threadIdx.x;
  int wg = blockIdx.x;            // b*256 + bi*16 + bj
  int bj = wg & 15, bi = (wg >> 4) & 15, b = wg >> 8;

  if (t < 9) {
    int di = t / 3 - 1, dj = t % 3 - 1;
    int ci = bi + di, cj = bj + dj;
    int sc = min(max(ci, 0), 15) * 16 + min(max(cj, 0), 15);
    bool valid = ((unsigned)ci < 16u) && ((unsigned)cj < 16u);
    scand[t] = valid ? sc : (-1 - sc);
  }
  for (int o = t; o < 144; o += 256) {   // 9 cents x 16 float4
    int k = o >> 4, f4 = o & 15;
    int di = k / 3 - 1, dj = k % 3 - 1;
    int sc = min(max(bi + di, 0), 15) * 16 + min(max(bj + dj, 0), 15);
    *(float4*)&cent_s[k * 64 + f4 * 4] =
        *(const float4*)(cent + (((b << 8) + sc) << 6) + f4 * 4);
  }
  __syncthreads();
  if (t < 72) {
    int k = t >> 3, pt = t & 7;
    float s = 0.f;
#pragma unroll
    for (int m = 0; m < 8; m++) { float v = cent_s[k * 64 + pt * 8 + m]; s += v * v; }
    c2p[t] = s;
  }
  __syncthreads();
  if (t < 9) {
    float s = 0.f;
#pragma unroll
    for (int m = 0; m < 8; m++) s += c2p[t * 8 + m];
    c2_s[t] = s;
  }
  __syncthreads();

  // valid bits (block-uniform, cheap per thread)
  int vbits = 0;
#pragma unroll
  for (int k = 0; k < 9; k++) {
    int ci = bi + k / 3 - 1, cj = bj + k % 3 - 1;
    if ((unsigned)ci < 16u && (unsigned)cj < 16u) vbits |= 1 << k;
  }

  // dot pass: thread t = pixel (r=t>>4, col=t&15); stash bf16 x into LDS
  int r = t >> 4, col = t & 15;
  const float* base = x + ((long)(b * 64) << 16) + ((bi * 16 + r) << 8) + (bj * 16 + col);
  float acc[9];
#pragma unroll
  for (int k = 0; k < 9; k++) acc[k] = 0.f;
#pragma unroll 4
  for (int c = 0; c < 64; c++) {
    float xv = base[(long)c << 16];
    xbf[c * 264 + t] = f2bf(xv);
#pragma unroll
    for (int k = 0; k < 9; k++) acc[k] = fmaf(xv, cent_s[k * 64 + c], acc[k]);
  }
  float mx = -1e30f;
#pragma unroll
  for (int k = 0; k < 9; k++) {
    float l = 2.f * acc[k] - c2_s[k];
    acc[k] = ((vbits >> k) & 1) ? l : -1e30f;
    mx = fmaxf(mx, acc[k]);
  }
  float sum = 0.f;
#pragma unroll
  for (int k = 0; k < 9; k++) {
    acc[k] = __expf(acc[k] - mx);
    sum += acc[k];
  }
  float rs = 1.f / sum;
#pragma unroll
  for (int k = 0; k < 9; k++) {
    acc[k] *= rs;
    affbf[k * 264 + t] = f2bf(acc[k]);
  }

  // den: full-wave shfl reduce per k (54 shfl/wave total)
  int lane = t & 63, w = t >> 6;
#pragma unroll
  for (int k = 0; k < 9; k++) {
    float v = acc[k];
    v += __shfl_xor(v, 1);
    v += __shfl_xor(v, 2);
    v += __shfl_xor(v, 4);
    v += __shfl_xor(v, 8);
    v += __shfl_xor(v, 16);
    v += __shfl_xor(v, 32);
    if (lane == 0) den_s[w * 9 + k] = v;
  }
  __syncthreads();
  if (t < 9) {
    float d = den_s[t] + den_s[9 + t] + den_s[18 + t] + den_s[27 + t];
    int sc = scand[t]; sc = sc >= 0 ? sc : (-1 - sc);
    atomicAdd(&den[(b << 8) + sc], d);
  }

  // num GEMM: wave w owns c-tile [16w,16w+16); 8 K-steps of 16x16x32 bf16 MFMA
  int mrow = lane & 15;   // A: m (c within tile); B: n (candidate k)
  int quad = lane >> 4;
  f32x4 dacc = {0.f, 0.f, 0.f, 0.f};
#pragma unroll
  for (int ks = 0; ks < 8; ks++) {
    int p0 = ks * 32 + quad * 8;
    short8 a = *(const short8*)&xbf[(w * 16 + mrow) * 264 + p0];
    short8 bf = *(const short8*)&affbf[mrow * 264 + p0];
    dacc = __builtin_amdgcn_mfma_f32_16x16x32_bf16(a, bf, dacc, 0, 0, 0);
  }
  // D[row=quad*4+reg][col=lane&15]: col = candidate k, row -> c
  int kcol = lane & 15;
  if (kcol < 9) {
    int sc = scand[kcol]; sc = sc >= 0 ? sc : (-1 - sc);
    float* np = num + (((b << 8) + sc) << 6) + w * 16 + quad * 4;
    atomicAdd(&np[0], dacc[0]);
    atomicAdd(&np[1], dacc[1]);
    atomicAdd(&np[2], dacc[2]);
    atomicAdd(&np[3], dacc[3]);
  }
}

// ---- out: finalize cents (num/den) + affinity for one row + write output ----
// grid 1024 = b(4) x i(256). Writes 256 s x 1KB contiguous per wg.  (round-3 proven)
__global__ __launch_bounds__(256) void k_out(const float* __restrict__ x,
                                             const float* __restrict__ num,
                                             const float* __restrict__ den,
                                             float4* __restrict__ out4) {
  __shared__ float cent_s[48 * 68];
  __shared__ float den_s[48];
  __shared__ float c2p[384];
  __shared__ float c2_s[48];
  __shared__ float aff_t[9 * 260];

  int t = threadIdx.x;
  int wg = blockIdx.x;
  int i = wg & 255, b = wg >> 8;
  int bi = i >> 4;

  if (t < 48) {
    int ci = min(max(bi - 1 + (t >> 4), 0), 15);
    int cj = t & 15;
    den_s[t] = den[(b << 8) + ci * 16 + cj] + 1e-16f;
  }
  __syncthreads();
  for (int o = t; o < 768; o += 256) {
    int lr = o >> 4, f4i = o & 15;
    int ci = min(max(bi - 1 + (lr >> 4), 0), 15);
    int cj = lr & 15;
    float4 v = *(const float4*)(num + (((b << 8) + ci * 16 + cj) << 6) + f4i * 4);
    float inv = 1.f / den_s[lr];
    v.x *= inv; v.y *= inv; v.z *= inv; v.w *= inv;
    *(float4*)&cent_s[lr * 68 + f4i * 4] = v;
  }
  __syncthreads();
  for (int o = t; o < 384; o += 256) {
    int lr = o >> 3, pt = o & 7;
    float s = 0.f;
#pragma unroll
    for (int m = 0; m < 8; m++) { float v = cent_s[lr * 68 + pt * 8 + m]; s += v * v; }
    c2p[o] = s;
  }
  __syncthreads();
  if (t < 48) {
    float s = 0.f;
#pragma unroll
    for (int m = 0; m < 8; m++) s += c2p[t * 8 + m];
    c2_s[t] = s;
  }
  __syncthreads();

  int j = t, bj = j >> 4;
  int cidx[9];
  float c2k[9];
  int vbits = 0;
#pragma unroll
  for (int k = 0; k < 9; k++) {
    int di = k / 3 - 1, dj = k % 3 - 1;
    int ciu = bi + di, cju = bj + dj;
    if ((unsigned)ciu < 16u && (unsigned)cju < 16u) vbits |= 1 << k;
    int lidx = (di + 1) * 16 + min(max(cju, 0), 15);
    cidx[k] = lidx * 68;
    c2k[k] = c2_s[lidx];
  }
  const float* base = x + ((long)(b * 64) << 16) + (i << 8) + j;
  float acc[9];
#pragma unroll
  for (int k = 0; k < 9; k++) acc[k] = 0.f;
#pragma unroll 4
  for (int c = 0; c < 64; c++) {
    float xv = base[(long)c << 16];
#pragma unroll
    for (int k = 0; k < 9; k++) acc[k] = fmaf(xv, cent_s[cidx[k] + c], acc[k]);
  }
  float mx = -1e30f;
#pragma unroll
  for (int k = 0; k < 9; k++) {
    float l = 2.f * acc[k] - c2k[k];
    acc[k] = ((vbits >> k) & 1) ? l : -1e30f;
    mx = fmaxf(mx, acc[k]);
  }
  float sum = 0.f;
#pragma unroll
  for (int k = 0; k < 9; k++) {
    acc[k] = __expf(acc[k] - mx);
    sum += acc[k];
  }
  float rs = 1.f / sum;
#pragma unroll
  for (int k = 0; k < 9; k++) aff_t[k * 260 + j] = acc[k] * rs;
  __syncthreads();

  float4* obase = out4 + ((long)(b << 8) << 14) + (i << 6) + (t & 63);
  int j4 = t & 63;
  int w = t >> 6;
#pragma unroll 4
  for (int m = 0; m < 64; m++) {
    int s = (m << 2) | w;
    float4 v = make_float4(0.f, 0.f, 0.f, 0.f);
    int di = (s >> 4) - bi;
    if ((unsigned)(di + 1) <= 2u) {
      int dj = (s & 15) - (j4 >> 2);
      if ((unsigned)(dj + 1) <= 2u) {
        int k = (di + 1) * 3 + dj + 1;
        v = *(const float4*)&aff_t[k * 260 + (j4 << 2)];
      }
    }
    obase[(long)s << 14] = v;
  }
}

extern "C" void kernel_launch(void* const* d_in, const int* in_sizes, int n_in,
                              void* d_out, int out_size, void* d_ws, size_t ws_size,
                              hipStream_t stream) {
  const float* x = (const float*)d_in[0];
  float* out = (float*)d_out;
  float* ws = (float*)d_ws;

  float* num   = ws;
  float* den   = ws + 65536;
  float* cent0 = ws + 66560;

  k_init<<<1024, 256, 0, stream>>>(x, cent0, (float4*)ws);
  k_stat<<<1024, 256, 0, stream>>>(x, cent0, num, den);
  k_out<<<1024, 256, 0, stream>>>(x, num, den, (float4*)out);
}

// Round 7
// 354.320 us; speedup vs baseline: 1.2877x; 1.0122x over previous
//
#include <hip/hip_runtime.h>

// GenSP: B=4, C=64, H=W=256, st=16 -> nH=nW=16, nS=256, P=65536
// out (B,nS,P) = 256MB dense, <=9 nonzeros per pixel column.
// M_COEF=0 -> grid channels zero; f2 (pixel norm) cancels in softmax.
// ws float layout: num[65536] den[1024] cent0[65536]

#define PP 65536

typedef __attribute__((ext_vector_type(8))) short short8;
typedef __attribute__((ext_vector_type(4))) float f32x4;

__device__ __forceinline__ unsigned short f2bf(float f) {
  unsigned u = __float_as_uint(f);
  u += 0x7fff + ((u >> 16) & 1);   // round-nearest-even
  return (unsigned short)(u >> 16);
}

// ---- init: 16x16 block means -> cent0[(b*256+s)*64+c]; zero num/den ----
__global__ __launch_bounds__(256) void k_init(const float* __restrict__ x,
                                              float* __restrict__ cent0,
                                              float4* __restrict__ zero4) {
  __shared__ float blk[64];
  int t = threadIdx.x;
  int wg = blockIdx.x;
  int cg = wg & 15, bi = (wg >> 4) & 15, b = wg >> 8;
  int tid = wg * 256 + t;
  if (tid < 16640) zero4[tid] = make_float4(0.f, 0.f, 0.f, 0.f);  // num+den
  if (t < 64) blk[t] = 0.f;
  __syncthreads();
  int sub = t >> 6, j4 = t & 63;
#pragma unroll
  for (int q = 0; q < 4; q++) {
    int c = cg * 4 + q;
    const float4* xp4 =
        (const float4*)(x + ((long)(b * 64 + c) << 16) + ((bi * 16 + sub * 4) << 8)) + j4;
    float4 a = make_float4(0.f, 0.f, 0.f, 0.f);
#pragma unroll
    for (int r = 0; r < 4; r++) {
      float4 v = xp4[r * 64];
      a.x += v.x; a.y += v.y; a.z += v.z; a.w += v.w;
    }
    float ps = a.x + a.y + a.z + a.w;
    ps += __shfl_xor(ps, 1);
    ps += __shfl_xor(ps, 2);
    if ((j4 & 3) == 0) atomicAdd(&blk[(j4 >> 2) * 4 + q], ps);
  }
  __syncthreads();
  if (t < 64) {
    int sj = t >> 2, q = t & 3;
    cent0[(((b << 8) + bi * 16 + sj) << 6) + cg * 4 + q] = blk[t] * (1.f / 256.f);
  }
}

// ---- stat: wg = one 16x16 block; dot+softmax scalar, num via bf16 MFMA ----
__global__ __launch_bounds__(256) void k_stat(const float* __restrict__ x,
                                              const float* __restrict__ cent,
                                              float* __restrict__ num,
                                              float* __restrict__ den) {
  __shared__ __align__(16) unsigned short xbf[64 * 264];
  __shared__ __align__(16) unsigned short affbf[16 * 264];
  __shared__ float cent_s[9 * 64];
  __shared__ float c2p[72];
  __shared__ float c2_s[9];
  __shared__ float den_s[36];
  __shared__ int scand[9];

  int t = threadIdx.x;
  int wg = blockIdx.x;            // b*256 + bi*16 + bj
  int bj = wg & 15, bi = (wg >> 4) & 15, b = wg >> 8;

  if (t < 9) {
    int di = t / 3 - 1, dj = t % 3 - 1;
    int ci = bi + di, cj = bj + dj;
    int sc = min(max(ci, 0), 15) * 16 + min(max(cj, 0), 15);
    bool valid = ((unsigned)ci < 16u) && ((unsigned)cj < 16u);
    scand[t] = valid ? sc : (-1 - sc);
  }
  for (int o = t; o < 144; o += 256) {
    int k = o >> 4, f4 = o & 15;
    int di = k / 3 - 1, dj = k % 3 - 1;
    int sc = min(max(bi + di, 0), 15) * 16 + min(max(bj + dj, 0), 15);
    *(float4*)&cent_s[k * 64 + f4 * 4] =
        *(const float4*)(cent + (((b << 8) + sc) << 6) + f4 * 4);
  }
  __syncthreads();
  if (t < 72) {
    int k = t >> 3, pt = t & 7;
    float s = 0.f;
#pragma unroll
    for (int m = 0; m < 8; m++) { float v = cent_s[k * 64 + pt * 8 + m]; s += v * v; }
    c2p[t] = s;
  }
  __syncthreads();
  if (t < 9) {
    float s = 0.f;
#pragma unroll
    for (int m = 0; m < 8; m++) s += c2p[t * 8 + m];
    c2_s[t] = s;
  }
  __syncthreads();

  int vbits = 0;
#pragma unroll
  for (int k = 0; k < 9; k++) {
    int ci = bi + k / 3 - 1, cj = bj + k % 3 - 1;
    if ((unsigned)ci < 16u && (unsigned)cj < 16u) vbits |= 1 << k;
  }

  int r = t >> 4, col = t & 15;
  const float* base = x + ((long)(b * 64) << 16) + ((bi * 16 + r) << 8) + (bj * 16 + col);
  float acc[9];
#pragma unroll
  for (int k = 0; k < 9; k++) acc[k] = 0.f;
#pragma unroll 8
  for (int c = 0; c < 64; c++) {
    float xv = base[(long)c << 16];
    xbf[c * 264 + t] = f2bf(xv);
#pragma unroll
    for (int k = 0; k < 9; k++) acc[k] = fmaf(xv, cent_s[k * 64 + c], acc[k]);
  }
  float mx = -1e30f;
#pragma unroll
  for (int k = 0; k < 9; k++) {
    float l = 2.f * acc[k] - c2_s[k];
    acc[k] = ((vbits >> k) & 1) ? l : -1e30f;
    mx = fmaxf(mx, acc[k]);
  }
  float sum = 0.f;
#pragma unroll
  for (int k = 0; k < 9; k++) {
    acc[k] = __expf(acc[k] - mx);
    sum += acc[k];
  }
  float rs = 1.f / sum;
#pragma unroll
  for (int k = 0; k < 9; k++) {
    acc[k] *= rs;
    affbf[k * 264 + t] = f2bf(acc[k]);
  }

  int lane = t & 63, w = t >> 6;
#pragma unroll
  for (int k = 0; k < 9; k++) {
    float v = acc[k];
    v += __shfl_xor(v, 1);
    v += __shfl_xor(v, 2);
    v += __shfl_xor(v, 4);
    v += __shfl_xor(v, 8);
    v += __shfl_xor(v, 16);
    v += __shfl_xor(v, 32);
    if (lane == 0) den_s[w * 9 + k] = v;
  }
  __syncthreads();
  if (t < 9) {
    float d = den_s[t] + den_s[9 + t] + den_s[18 + t] + den_s[27 + t];
    int sc = scand[t]; sc = sc >= 0 ? sc : (-1 - sc);
    atomicAdd(&den[(b << 8) + sc], d);
  }

  // num GEMM: wave w owns c-tile [16w,16w+16); 8 K-steps of 16x16x32 bf16 MFMA
  int mrow = lane & 15;
  int quad = lane >> 4;
  f32x4 dacc = {0.f, 0.f, 0.f, 0.f};
#pragma unroll
  for (int ks = 0; ks < 8; ks++) {
    int p0 = ks * 32 + quad * 8;
    short8 a = *(const short8*)&xbf[(w * 16 + mrow) * 264 + p0];
    short8 bf = *(const short8*)&affbf[mrow * 264 + p0];
    dacc = __builtin_amdgcn_mfma_f32_16x16x32_bf16(a, bf, dacc, 0, 0, 0);
  }
  int kcol = lane & 15;
  if (kcol < 9) {
    int sc = scand[kcol]; sc = sc >= 0 ? sc : (-1 - sc);
    float* np = num + (((b << 8) + sc) << 6) + w * 16 + quad * 4;
    atomicAdd(&np[0], dacc[0]);
    atomicAdd(&np[1], dacc[1]);
    atomicAdd(&np[2], dacc[2]);
    atomicAdd(&np[3], dacc[3]);
  }
}

// ---- out: finalize cents + affinity for one row + write half the s-planes ----
// grid 2048 = b(4) x i(256) x h(2). Each wg: full row aff (x is L3-warm),
// stores s in [h*128, h*128+128): 32 store iters/thread.
__global__ __launch_bounds__(256) void k_out(const float* __restrict__ x,
                                             const float* __restrict__ num,
                                             const float* __restrict__ den,
                                             float4* __restrict__ out4) {
  __shared__ float cent_s[48 * 68];
  __shared__ float den_s[48];
  __shared__ float c2p[384];
  __shared__ float c2_s[48];
  __shared__ float aff_t[9 * 260];

  int t = threadIdx.x;
  int wg = blockIdx.x;
  int h = wg & 1, i = (wg >> 1) & 255, b = wg >> 9;
  int bi = i >> 4;

  if (t < 48) {
    int ci = min(max(bi - 1 + (t >> 4), 0), 15);
    int cj = t & 15;
    den_s[t] = den[(b << 8) + ci * 16 + cj] + 1e-16f;
  }
  __syncthreads();
  for (int o = t; o < 768; o += 256) {
    int lr = o >> 4, f4i = o & 15;
    int ci = min(max(bi - 1 + (lr >> 4), 0), 15);
    int cj = lr & 15;
    float4 v = *(const float4*)(num + (((b << 8) + ci * 16 + cj) << 6) + f4i * 4);
    float inv = 1.f / den_s[lr];
    v.x *= inv; v.y *= inv; v.z *= inv; v.w *= inv;
    *(float4*)&cent_s[lr * 68 + f4i * 4] = v;
  }
  __syncthreads();
  for (int o = t; o < 384; o += 256) {
    int lr = o >> 3, pt = o & 7;
    float s = 0.f;
#pragma unroll
    for (int m = 0; m < 8; m++) { float v = cent_s[lr * 68 + pt * 8 + m]; s += v * v; }
    c2p[o] = s;
  }
  __syncthreads();
  if (t < 48) {
    float s = 0.f;
#pragma unroll
    for (int m = 0; m < 8; m++) s += c2p[t * 8 + m];
    c2_s[t] = s;
  }
  __syncthreads();

  int j = t, bj = j >> 4;
  int cidx[9];
  float c2k[9];
  int vbits = 0;
#pragma unroll
  for (int k = 0; k < 9; k++) {
    int di = k / 3 - 1, dj = k % 3 - 1;
    int ciu = bi + di, cju = bj + dj;
    if ((unsigned)ciu < 16u && (unsigned)cju < 16u) vbits |= 1 << k;
    int lidx = (di + 1) * 16 + min(max(cju, 0), 15);
    cidx[k] = lidx * 68;
    c2k[k] = c2_s[lidx];
  }
  const float* base = x + ((long)(b * 64) << 16) + (i << 8) + j;
  float acc[9];
#pragma unroll
  for (int k = 0; k < 9; k++) acc[k] = 0.f;
#pragma unroll 8
  for (int c = 0; c < 64; c++) {
    float xv = base[(long)c << 16];
#pragma unroll
    for (int k = 0; k < 9; k++) acc[k] = fmaf(xv, cent_s[cidx[k] + c], acc[k]);
  }
  float mx = -1e30f;
#pragma unroll
  for (int k = 0; k < 9; k++) {
    float l = 2.f * acc[k] - c2k[k];
    acc[k] = ((vbits >> k) & 1) ? l : -1e30f;
    mx = fmaxf(mx, acc[k]);
  }
  float sum = 0.f;
#pragma unroll
  for (int k = 0; k < 9; k++) {
    acc[k] = __expf(acc[k] - mx);
    sum += acc[k];
  }
  float rs = 1.f / sum;
#pragma unroll
  for (int k = 0; k < 9; k++) aff_t[k * 260 + j] = acc[k] * rs;
  __syncthreads();

  // phase B: s in [h*128, h*128+128), wave w handles s = s0 + (m<<2)|w
  float4* obase = out4 + ((long)(b << 8) << 14) + (i << 6) + (t & 63);
  int j4 = t & 63;
  int w = t >> 6;
  int s0 = h << 7;
#pragma unroll 4
  for (int m = 0; m < 32; m++) {
    int s = s0 | (m << 2) | w;
    float4 v = make_float4(0.f, 0.f, 0.f, 0.f);
    int di = (s >> 4) - bi;
    if ((unsigned)(di + 1) <= 2u) {
      int dj = (s & 15) - (j4 >> 2);
      if ((unsigned)(dj + 1) <= 2u) {
        int k = (di + 1) * 3 + dj + 1;
        v = *(const float4*)&aff_t[k * 260 + (j4 << 2)];
      }
    }
    obase[(long)s << 14] = v;
  }
}

extern "C" void kernel_launch(void* const* d_in, const int* in_sizes, int n_in,
                              void* d_out, int out_size, void* d_ws, size_t ws_size,
                              hipStream_t stream) {
  const float* x = (const float*)d_in[0];
  float* out = (float*)d_out;
  float* ws = (float*)d_ws;

  float* num   = ws;
  float* den   = ws + 65536;
  float* cent0 = ws + 66560;

  k_init<<<1024, 256, 0, stream>>>(x, cent0, (float4*)ws);
  k_stat<<<1024, 256, 0, stream>>>(x, cent0, num, den);
  k_out<<<2048, 256, 0, stream>>>(x, num, den, (float4*)out);
}

// Round 8
// 353.851 us; speedup vs baseline: 1.2894x; 1.0013x over previous
//
#include <hip/hip_runtime.h>

// GenSP: B=4, C=64, H=W=256, st=16 -> nH=nW=16, nS=256, P=65536
// out (B,nS,P) = 256MB dense, <=9 nonzeros per pixel column.
// M_COEF=0 -> grid channels zero; f2 (pixel norm) cancels in softmax.
// ws float layout: num[65536] den[1024] cent0[65536]

#define PP 65536

typedef __attribute__((ext_vector_type(8))) short short8;
typedef __attribute__((ext_vector_type(4))) float f32x4;

__device__ __forceinline__ unsigned short f2bf(float f) {
  unsigned u = __float_as_uint(f);
  u += 0x7fff + ((u >> 16) & 1);   // round-nearest-even
  return (unsigned short)(u >> 16);
}

// ---- init: 16x16 block means -> cent0[(b*256+s)*64+c]; zero num/den ----
__global__ __launch_bounds__(256) void k_init(const float* __restrict__ x,
                                              float* __restrict__ cent0,
                                              float4* __restrict__ zero4) {
  __shared__ float blk[64];
  int t = threadIdx.x;
  int wg = blockIdx.x;
  int cg = wg & 15, bi = (wg >> 4) & 15, b = wg >> 8;
  int tid = wg * 256 + t;
  if (tid < 16640) zero4[tid] = make_float4(0.f, 0.f, 0.f, 0.f);  // num+den
  if (t < 64) blk[t] = 0.f;
  __syncthreads();
  int sub = t >> 6, j4 = t & 63;
#pragma unroll
  for (int q = 0; q < 4; q++) {
    int c = cg * 4 + q;
    const float4* xp4 =
        (const float4*)(x + ((long)(b * 64 + c) << 16) + ((bi * 16 + sub * 4) << 8)) + j4;
    float4 a = make_float4(0.f, 0.f, 0.f, 0.f);
#pragma unroll
    for (int r = 0; r < 4; r++) {
      float4 v = xp4[r * 64];
      a.x += v.x; a.y += v.y; a.z += v.z; a.w += v.w;
    }
    float ps = a.x + a.y + a.z + a.w;
    ps += __shfl_xor(ps, 1);
    ps += __shfl_xor(ps, 2);
    if ((j4 & 3) == 0) atomicAdd(&blk[(j4 >> 2) * 4 + q], ps);
  }
  __syncthreads();
  if (t < 64) {
    int sj = t >> 2, q = t & 3;
    cent0[(((b << 8) + bi * 16 + sj) << 6) + cg * 4 + q] = blk[t] * (1.f / 256.f);
  }
}

// ---- stat: wg = one 16x16 block; dot+softmax scalar, num via bf16 MFMA ----
__global__ __launch_bounds__(256) void k_stat(const float* __restrict__ x,
                                              const float* __restrict__ cent,
                                              float* __restrict__ num,
                                              float* __restrict__ den) {
  __shared__ __align__(16) unsigned short xbf[64 * 264];
  __shared__ __align__(16) unsigned short affbf[16 * 264];
  __shared__ float cent_s[9 * 64];
  __shared__ float c2p[72];
  __shared__ float c2_s[9];
  __shared__ float den_s[36];
  __shared__ int scand[9];

  int t = threadIdx.x;
  int wg = blockIdx.x;            // b*256 + bi*16 + bj
  int bj = wg & 15, bi = (wg >> 4) & 15, b = wg >> 8;

  if (t < 9) {
    int di = t / 3 - 1, dj = t % 3 - 1;
    int ci = bi + di, cj = bj + dj;
    int sc = min(max(ci, 0), 15) * 16 + min(max(cj, 0), 15);
    bool valid = ((unsigned)ci < 16u) && ((unsigned)cj < 16u);
    scand[t] = valid ? sc : (-1 - sc);
  }
  for (int o = t; o < 144; o += 256) {
    int k = o >> 4, f4 = o & 15;
    int di = k / 3 - 1, dj = k % 3 - 1;
    int sc = min(max(bi + di, 0), 15) * 16 + min(max(bj + dj, 0), 15);
    *(float4*)&cent_s[k * 64 + f4 * 4] =
        *(const float4*)(cent + (((b << 8) + sc) << 6) + f4 * 4);
  }
  __syncthreads();
  if (t < 72) {
    int k = t >> 3, pt = t & 7;
    float s = 0.f;
#pragma unroll
    for (int m = 0; m < 8; m++) { float v = cent_s[k * 64 + pt * 8 + m]; s += v * v; }
    c2p[t] = s;
  }
  __syncthreads();
  if (t < 9) {
    float s = 0.f;
#pragma unroll
    for (int m = 0; m < 8; m++) s += c2p[t * 8 + m];
    c2_s[t] = s;
  }
  __syncthreads();

  int vbits = 0;
#pragma unroll
  for (int k = 0; k < 9; k++) {
    int ci = bi + k / 3 - 1, cj = bj + k % 3 - 1;
    if ((unsigned)ci < 16u && (unsigned)cj < 16u) vbits |= 1 << k;
  }

  int r = t >> 4, col = t & 15;
  const float* base = x + ((long)(b * 64) << 16) + ((bi * 16 + r) << 8) + (bj * 16 + col);
  float acc[9];
#pragma unroll
  for (int k = 0; k < 9; k++) acc[k] = 0.f;
#pragma unroll 8
  for (int c = 0; c < 64; c++) {
    float xv = base[(long)c << 16];
    xbf[c * 264 + t] = f2bf(xv);
#pragma unroll
    for (int k = 0; k < 9; k++) acc[k] = fmaf(xv, cent_s[k * 64 + c], acc[k]);
  }
  float mx = -1e30f;
#pragma unroll
  for (int k = 0; k < 9; k++) {
    float l = 2.f * acc[k] - c2_s[k];
    acc[k] = ((vbits >> k) & 1) ? l : -1e30f;
    mx = fmaxf(mx, acc[k]);
  }
  float sum = 0.f;
#pragma unroll
  for (int k = 0; k < 9; k++) {
    acc[k] = __expf(acc[k] - mx);
    sum += acc[k];
  }
  float rs = 1.f / sum;
#pragma unroll
  for (int k = 0; k < 9; k++) {
    acc[k] *= rs;
    affbf[k * 264 + t] = f2bf(acc[k]);
  }

  int lane = t & 63, w = t >> 6;
#pragma unroll
  for (int k = 0; k < 9; k++) {
    float v = acc[k];
    v += __shfl_xor(v, 1);
    v += __shfl_xor(v, 2);
    v += __shfl_xor(v, 4);
    v += __shfl_xor(v, 8);
    v += __shfl_xor(v, 16);
    v += __shfl_xor(v, 32);
    if (lane == 0) den_s[w * 9 + k] = v;
  }
  __syncthreads();
  if (t < 9) {
    float d = den_s[t] + den_s[9 + t] + den_s[18 + t] + den_s[27 + t];
    int sc = scand[t]; sc = sc >= 0 ? sc : (-1 - sc);
    atomicAdd(&den[(b << 8) + sc], d);
  }

  // num GEMM: wave w owns c-tile [16w,16w+16); 8 K-steps of 16x16x32 bf16 MFMA
  int mrow = lane & 15;
  int quad = lane >> 4;
  f32x4 dacc = {0.f, 0.f, 0.f, 0.f};
#pragma unroll
  for (int ks = 0; ks < 8; ks++) {
    int p0 = ks * 32 + quad * 8;
    short8 a = *(const short8*)&xbf[(w * 16 + mrow) * 264 + p0];
    short8 bf = *(const short8*)&affbf[mrow * 264 + p0];
    dacc = __builtin_amdgcn_mfma_f32_16x16x32_bf16(a, bf, dacc, 0, 0, 0);
  }
  int kcol = lane & 15;
  if (kcol < 9) {
    int sc = scand[kcol]; sc = sc >= 0 ? sc : (-1 - sc);
    float* np = num + (((b << 8) + sc) << 6) + w * 16 + quad * 4;
    atomicAdd(&np[0], dacc[0]);
    atomicAdd(&np[1], dacc[1]);
    atomicAdd(&np[2], dacc[2]);
    atomicAdd(&np[3], dacc[3]);
  }
}

// ---- out: finalize cents + affinity for one row + write half the s-planes ----
// grid 2048 = b(4) x i(256) x h(2). Output stores are NON-TEMPORAL (nt):
// out is write-once, never re-read; keeping it out of L2/L3 preserves x
// residency for the in-kernel re-reads.
__global__ __launch_bounds__(256) void k_out(const float* __restrict__ x,
                                             const float* __restrict__ num,
                                             const float* __restrict__ den,
                                             f32x4* __restrict__ out4) {
  __shared__ float cent_s[48 * 68];
  __shared__ float den_s[48];
  __shared__ float c2p[384];
  __shared__ float c2_s[48];
  __shared__ float aff_t[9 * 260];

  int t = threadIdx.x;
  int wg = blockIdx.x;
  int h = wg & 1, i = (wg >> 1) & 255, b = wg >> 9;
  int bi = i >> 4;

  if (t < 48) {
    int ci = min(max(bi - 1 + (t >> 4), 0), 15);
    int cj = t & 15;
    den_s[t] = den[(b << 8) + ci * 16 + cj] + 1e-16f;
  }
  __syncthreads();
  for (int o = t; o < 768; o += 256) {
    int lr = o >> 4, f4i = o & 15;
    int ci = min(max(bi - 1 + (lr >> 4), 0), 15);
    int cj = lr & 15;
    float4 v = *(const float4*)(num + (((b << 8) + ci * 16 + cj) << 6) + f4i * 4);
    float inv = 1.f / den_s[lr];
    v.x *= inv; v.y *= inv; v.z *= inv; v.w *= inv;
    *(float4*)&cent_s[lr * 68 + f4i * 4] = v;
  }
  __syncthreads();
  for (int o = t; o < 384; o += 256) {
    int lr = o >> 3, pt = o & 7;
    float s = 0.f;
#pragma unroll
    for (int m = 0; m < 8; m++) { float v = cent_s[lr * 68 + pt * 8 + m]; s += v * v; }
    c2p[o] = s;
  }
  __syncthreads();
  if (t < 48) {
    float s = 0.f;
#pragma unroll
    for (int m = 0; m < 8; m++) s += c2p[t * 8 + m];
    c2_s[t] = s;
  }
  __syncthreads();

  int j = t, bj = j >> 4;
  int cidx[9];
  float c2k[9];
  int vbits = 0;
#pragma unroll
  for (int k = 0; k < 9; k++) {
    int di = k / 3 - 1, dj = k % 3 - 1;
    int ciu = bi + di, cju = bj + dj;
    if ((unsigned)ciu < 16u && (unsigned)cju < 16u) vbits |= 1 << k;
    int lidx = (di + 1) * 16 + min(max(cju, 0), 15);
    cidx[k] = lidx * 68;
    c2k[k] = c2_s[lidx];
  }
  const float* base = x + ((long)(b * 64) << 16) + (i << 8) + j;
  float acc[9];
#pragma unroll
  for (int k = 0; k < 9; k++) acc[k] = 0.f;
#pragma unroll 8
  for (int c = 0; c < 64; c++) {
    float xv = base[(long)c << 16];
#pragma unroll
    for (int k = 0; k < 9; k++) acc[k] = fmaf(xv, cent_s[cidx[k] + c], acc[k]);
  }
  float mx = -1e30f;
#pragma unroll
  for (int k = 0; k < 9; k++) {
    float l = 2.f * acc[k] - c2k[k];
    acc[k] = ((vbits >> k) & 1) ? l : -1e30f;
    mx = fmaxf(mx, acc[k]);
  }
  float sum = 0.f;
#pragma unroll
  for (int k = 0; k < 9; k++) {
    acc[k] = __expf(acc[k] - mx);
    sum += acc[k];
  }
  float rs = 1.f / sum;
#pragma unroll
  for (int k = 0; k < 9; k++) aff_t[k * 260 + j] = acc[k] * rs;
  __syncthreads();

  // phase B: s in [h*128, h*128+128), wave w handles s = s0 + (m<<2)|w
  f32x4* obase = out4 + ((long)(b << 8) << 14) + (i << 6) + (t & 63);
  int j4 = t & 63;
  int w = t >> 6;
  int s0 = h << 7;
#pragma unroll 4
  for (int m = 0; m < 32; m++) {
    int s = s0 | (m << 2) | w;
    f32x4 v = {0.f, 0.f, 0.f, 0.f};
    int di = (s >> 4) - bi;
    if ((unsigned)(di + 1) <= 2u) {
      int dj = (s & 15) - (j4 >> 2);
      if ((unsigned)(dj + 1) <= 2u) {
        int k = (di + 1) * 3 + dj + 1;
        v = *(const f32x4*)&aff_t[k * 260 + (j4 << 2)];
      }
    }
    __builtin_nontemporal_store(v, &obase[(long)s << 14]);
  }
}

extern "C" void kernel_launch(void* const* d_in, const int* in_sizes, int n_in,
                              void* d_out, int out_size, void* d_ws, size_t ws_size,
                              hipStream_t stream) {
  const float* x = (const float*)d_in[0];
  float* out = (float*)d_out;
  float* ws = (float*)d_ws;

  float* num   = ws;
  float* den   = ws + 65536;
  float* cent0 = ws + 66560;

  k_init<<<1024, 256, 0, stream>>>(x, cent0, (float4*)ws);
  k_stat<<<1024, 256, 0, stream>>>(x, cent0, num, den);
  k_out<<<2048, 256, 0, stream>>>(x, num, den, (f32x4*)out);
}